// Round 8
// baseline (128.772 us; speedup 1.0000x reference)
//
#include <hip/hip_runtime.h>
#include <hip/hip_fp16.h>
#include <cstdint>
#include <cstddef>

// 2-layer GCN. norm factorization: out[d] = dinv[d]*(h_s[d] + sum_{s->d} h_s[s]),
// h_s[i] = dinv[i]*(x@W)[i]. Self-loop folded in as the h_s[d] term.
// Deterministic 2-level counting sort -> ushort CSR -> per-node gather (fp16 rows,
// f32 accumulate). GEMM2 fused into the layer-1 gather epilogue. 6 kernels total.

#define SHIFT 8                 // 256 nodes per coarse bucket
#define NPB 256
#define CHUNK 4096              // edges per histogram/scatter block
#define IMG_CAP 6144            // LDS csr-image capacity (avg bucket load ~4081)

// ---- K1: per-block bucket histogram. hist[b*nWG + w] = count of bucket b in block w ----
__global__ __launch_bounds__(256) void hist_kernel(const int* __restrict__ dst, int E, int nWG,
                                                   int B, int* __restrict__ hist) {
  __shared__ int h[256];
  int t = threadIdx.x, w = blockIdx.x;
  for (int i = t; i < B; i += 256) h[i] = 0;
  __syncthreads();
  int beg = w * CHUNK, end = min(beg + CHUNK, E);
  for (int i = beg + t; i < end; i += 256) atomicAdd(&h[dst[i] >> SHIFT], 1);
  __syncthreads();
  for (int i = t; i < B; i += 256) hist[i * nWG + w] = h[i];
}

// ---- K2: LDS-staged scatter of packed keys (bucket<<24 | local<<16 | src) ----
// Computes its own row-prefix/base from hist in-block (no rowscan kernel).
__global__ __launch_bounds__(256) void scatterkeys_kernel(const int* __restrict__ src,
                                                          const int* __restrict__ dst, int E, int nWG,
                                                          int B, const int* __restrict__ hist,
                                                          unsigned* __restrict__ keys) {
  __shared__ int loffs[256], cur[256], gb[256];
  __shared__ int wsum[4];
  __shared__ unsigned image[CHUNK];  // 16 KB
  int t = threadIdx.x, w = blockIdx.x;
  int lane = t & 63, wid = t >> 6;
  // per-thread walk of hist row t: total, prefix (blocks < w), own count
  int tot = 0, rp = 0, myc = 0;
  if (t < B) {
    const int* row = hist + (size_t)t * nWG;
    for (int w2 = 0; w2 < nWG; ++w2) {
      int v = row[w2];
      tot += v;
      if (w2 < w) rp += v;
      if (w2 == w) myc = v;
    }
  }
  // exclusive scan of tot over t -> base; gb[t] = base + rp
  {
    int x = tot;
#pragma unroll
    for (int o = 1; o < 64; o <<= 1) { int y = __shfl_up(x, o, 64); if (lane >= o) x += y; }
    if (lane == 63) wsum[wid] = x;
    __syncthreads();
    int bw = 0;
    for (int i = 0; i < wid; ++i) bw += wsum[i];
    if (t < B) gb[t] = bw + x - tot + rp;
  }
  __syncthreads();
  // exclusive scan of myc over t -> loffs/cur
  {
    int x = myc;
#pragma unroll
    for (int o = 1; o < 64; o <<= 1) { int y = __shfl_up(x, o, 64); if (lane >= o) x += y; }
    if (lane == 63) wsum[wid] = x;
    __syncthreads();
    int bw = 0;
    for (int i = 0; i < wid; ++i) bw += wsum[i];
    if (t < B) { loffs[t] = bw + x - myc; cur[t] = bw + x - myc; }
  }
  __syncthreads();
  // place into LDS image (position within block-local bucket run)
  int beg = w * CHUNK, end = min(beg + CHUNK, E);
  for (int i = beg + t; i < end; i += 256) {
    int d = dst[i], s = src[i];
    int b = d >> SHIFT;
    int p = atomicAdd(&cur[b], 1);
    image[p] = ((unsigned)b << 24) | ((unsigned)(d & (NPB - 1)) << 16) | (unsigned)s;
  }
  __syncthreads();
  // sequential write-out: dest = gb[b] + (i - loffs[b])
  int n = end - beg;
  for (int i = t; i < n; i += 256) {
    unsigned k = image[i];
    int b = (int)(k >> 24);
    keys[gb[b] + (i - loffs[b])] = k;
  }
}

// ---- K3: per-bucket: per-node counts -> eoff/ecnt/dinv; sort keys -> ushort csr ----
__global__ __launch_bounds__(256) void bucket_build_kernel(const unsigned* __restrict__ keys,
                                                           const int* __restrict__ hist, int nWG,
                                                           int B, int N,
                                                           unsigned short* __restrict__ csr,
                                                           int* __restrict__ eoff,
                                                           int* __restrict__ ecnt,
                                                           float* __restrict__ dinv) {
  __shared__ int cnt[NPB], loffs[NPB], cur[NPB];
  __shared__ int tsum[256];
  __shared__ int red[4];
  __shared__ int image[IMG_CAP];
  int b = blockIdx.x, t = threadIdx.x;
  int lane = t & 63, wid = t >> 6;
  // row sums of hist -> tsum
  int tot = 0;
  if (t < B) {
    const int* row = hist + (size_t)t * nWG;
    for (int w2 = 0; w2 < nWG; ++w2) tot += row[w2];
  }
  tsum[t] = tot;
  __syncthreads();
  // gbeg = sum_{i<b} tsum[i]
  int part = 0;
  for (int i = t; i < b; i += 256) part += tsum[i];
#pragma unroll
  for (int o = 32; o > 0; o >>= 1) part += __shfl_down(part, o, 64);
  if (lane == 0) red[wid] = part;
  __syncthreads();
  int gbeg = red[0] + red[1] + red[2] + red[3];
  int m = tsum[b];
  int gend = gbeg + m;
  int nb = b << SHIFT;
  int nn = min(NPB, N - nb);
  cnt[t] = 0;  // NPB == blockDim
  __syncthreads();
  for (int i = gbeg + t; i < gend; i += 256) atomicAdd(&cnt[(keys[i] >> 16) & 0xFF], 1);
  __syncthreads();
  if (t < 64) {  // 4-per-lane exclusive scan of cnt[0..255] in one wave
    int v0 = cnt[4 * t], v1 = cnt[4 * t + 1], v2 = cnt[4 * t + 2], v3 = cnt[4 * t + 3];
    int s = v0 + v1 + v2 + v3, x = s;
#pragma unroll
    for (int o = 1; o < 64; o <<= 1) { int y = __shfl_up(x, o, 64); if (t >= o) x += y; }
    int e = x - s;
    loffs[4 * t] = e;                 cur[4 * t] = e;
    loffs[4 * t + 1] = e + v0;        cur[4 * t + 1] = e + v0;
    loffs[4 * t + 2] = e + v0 + v1;   cur[4 * t + 2] = e + v0 + v1;
    loffs[4 * t + 3] = e + v0 + v1 + v2; cur[4 * t + 3] = e + v0 + v1 + v2;
  }
  __syncthreads();
  for (int n2 = t; n2 < nn; n2 += 256) {
    eoff[nb + n2] = gbeg + loffs[n2];
    ecnt[nb + n2] = cnt[n2];
    dinv[nb + n2] = 1.0f / sqrtf((float)(cnt[n2] + 1));  // +1 self-loop
  }
  if (m <= IMG_CAP) {
    for (int i = gbeg + t; i < gend; i += 256) {
      unsigned k = keys[i];
      int p = atomicAdd(&cur[(k >> 16) & 0xFF], 1);
      image[p] = (int)(k & 0xFFFFu);
    }
    __syncthreads();
    for (int i = t; i < m; i += 256) csr[gbeg + i] = (unsigned short)image[i];
  } else {  // statistically unreachable fallback
    for (int i = gbeg + t; i < gend; i += 256) {
      unsigned k = keys[i];
      int p = atomicAdd(&cur[(k >> 16) & 0xFF], 1);
      csr[gbeg + p] = (unsigned short)(k & 0xFFFFu);
    }
  }
}

// ---- GEMM1: h1s[i][c] = fp16( dinv[i] * (x @ W1)[i][c] )   (N x 128 @ 128 x 64) ----
__global__ __launch_bounds__(256) void gemm1_kernel(
    const float* __restrict__ x, const float* __restrict__ W1,
    const float* __restrict__ dinv, __half* __restrict__ h1s, int N) {
  __shared__ float ws[128 * 64];
  __shared__ float xs[64 * 128];
  const int t = threadIdx.x;
  const int rowBase = blockIdx.x * 64;
  float4* ws4 = (float4*)ws;
  float4* xs4 = (float4*)xs;
  for (int i = t; i < 128 * 16; i += 256) ws4[i] = ((const float4*)W1)[i];
  for (int i = t; i < 64 * 32; i += 256) {
    int r = i >> 5, kq = i & 31;
    int row = rowBase + r;
    float4 v = make_float4(0.f, 0.f, 0.f, 0.f);
    if (row < N) v = ((const float4*)x)[(size_t)row * 32 + kq];
    xs4[r * 32 + (kq ^ ((r >> 2) & 7))] = v;
  }
  __syncthreads();
  const int g = t & 15;
  const int rg = t >> 4;
  const int swz = rg & 7;
  float acc[4][4] = {};
  for (int kq = 0; kq < 32; ++kq) {
    float4 a[4];
#pragma unroll
    for (int j = 0; j < 4; ++j) a[j] = xs4[(4 * rg + j) * 32 + (kq ^ swz)];
    float4 w[4];
#pragma unroll
    for (int kk = 0; kk < 4; ++kk) w[kk] = ws4[(4 * kq + kk) * 16 + g];
#pragma unroll
    for (int j = 0; j < 4; ++j) {
      acc[j][0] += a[j].x * w[0].x + a[j].y * w[1].x + a[j].z * w[2].x + a[j].w * w[3].x;
      acc[j][1] += a[j].x * w[0].y + a[j].y * w[1].y + a[j].z * w[2].y + a[j].w * w[3].y;
      acc[j][2] += a[j].x * w[0].z + a[j].y * w[1].z + a[j].z * w[2].z + a[j].w * w[3].z;
      acc[j][3] += a[j].x * w[0].w + a[j].y * w[1].w + a[j].z * w[2].w + a[j].w * w[3].w;
    }
  }
#pragma unroll
  for (int j = 0; j < 4; ++j) {
    int row = rowBase + 4 * rg + j;
    if (row < N) {
      float dv = dinv[row];
      union { __half2 h2[2]; float2 f2v; } u;
      u.h2[0] = __floats2half2_rn(acc[j][0] * dv, acc[j][1] * dv);
      u.h2[1] = __floats2half2_rn(acc[j][2] * dv, acc[j][3] * dv);
      ((float2*)h1s)[(size_t)row * 16 + g] = u.f2v;
    }
  }
}

// ---- gather layer 1 + fused GEMM2 ----
// 16 lanes/node (lane holds 4 fp16 = 8 B), 16 nodes/block, 16-deep ILP, f32 accum.
// Epilogue: a1 row -> LDS; h2s[d][c] = fp16( dinv[d]*(relu(agg*dinv+b1) @ W2)[c] ).
__global__ __launch_bounds__(256) void gather64_gemm2_kernel(
    const __half* __restrict__ h1s, const unsigned short* __restrict__ csr,
    const int* __restrict__ eoff, const int* __restrict__ ecnt,
    const float* __restrict__ dinv, const float* __restrict__ b1,
    const float* __restrict__ W2, __half* __restrict__ h2s, int N) {
  __shared__ float w2s[64 * 32];   // 8 KB, [k][c]
  __shared__ float arow[16 * 64];  // 4 KB, per-slot a1 row
  int t = threadIdx.x;
  float4* w2s4 = (float4*)w2s;
  for (int i = t; i < 512; i += 256) w2s4[i] = ((const float4*)W2)[i];
  __syncthreads();  // all threads participate before any divergent exit
  int slot = t >> 4;               // 0..15
  int d = blockIdx.x * 16 + slot;
  if (d >= N) return;
  int f = t & 15;                  // 4-feat group: feats 4f..4f+3
  const float2* h1p = (const float2*)h1s;  // row stride 16 x 8B
  int beg = eoff[d], m = ecnt[d];
  float acc[4][4] = {};
  {  // self-loop
    union { float2 f2v; __half2 h2[2]; } u;
    u.f2v = h1p[(size_t)d * 16 + f];
    float2 lo = __half22float2(u.h2[0]), hi = __half22float2(u.h2[1]);
    acc[0][0] = lo.x; acc[0][1] = lo.y; acc[0][2] = hi.x; acc[0][3] = hi.y;
  }
  int j = 0;
  for (; j + 16 <= m; j += 16) {
    int s_[16];
#pragma unroll
    for (int i = 0; i < 16; ++i) s_[i] = csr[beg + j + i];
    float2 v_[16];
#pragma unroll
    for (int i = 0; i < 16; ++i) v_[i] = h1p[(size_t)s_[i] * 16 + f];
#pragma unroll
    for (int i = 0; i < 16; ++i) {
      union { float2 f2v; __half2 h2[2]; } u; u.f2v = v_[i];
      float2 lo = __half22float2(u.h2[0]), hi = __half22float2(u.h2[1]);
      acc[i & 3][0] += lo.x; acc[i & 3][1] += lo.y; acc[i & 3][2] += hi.x; acc[i & 3][3] += hi.y;
    }
  }
  for (; j + 4 <= m; j += 4) {
    int s_[4];
#pragma unroll
    for (int i = 0; i < 4; ++i) s_[i] = csr[beg + j + i];
    float2 v_[4];
#pragma unroll
    for (int i = 0; i < 4; ++i) v_[i] = h1p[(size_t)s_[i] * 16 + f];
#pragma unroll
    for (int i = 0; i < 4; ++i) {
      union { float2 f2v; __half2 h2[2]; } u; u.f2v = v_[i];
      float2 lo = __half22float2(u.h2[0]), hi = __half22float2(u.h2[1]);
      acc[i][0] += lo.x; acc[i][1] += lo.y; acc[i][2] += hi.x; acc[i][3] += hi.y;
    }
  }
  for (; j < m; ++j) {
    union { float2 f2v; __half2 h2[2]; } u;
    u.f2v = h1p[(size_t)csr[beg + j] * 16 + f];
    float2 lo = __half22float2(u.h2[0]), hi = __half22float2(u.h2[1]);
    acc[0][0] += lo.x; acc[0][1] += lo.y; acc[0][2] += hi.x; acc[0][3] += hi.y;
  }
  float g0 = (acc[0][0] + acc[1][0]) + (acc[2][0] + acc[3][0]);
  float g1 = (acc[0][1] + acc[1][1]) + (acc[2][1] + acc[3][1]);
  float g2 = (acc[0][2] + acc[1][2]) + (acc[2][2] + acc[3][2]);
  float g3 = (acc[0][3] + acc[1][3]) + (acc[2][3] + acc[3][3]);
  float dv = dinv[d];
  float4 bb = ((const float4*)b1)[f];
  float4 a1v;
  a1v.x = fmaxf(g0 * dv + bb.x, 0.f);
  a1v.y = fmaxf(g1 * dv + bb.y, 0.f);
  a1v.z = fmaxf(g2 * dv + bb.z, 0.f);
  a1v.w = fmaxf(g3 * dv + bb.w, 0.f);
  ((float4*)arow)[slot * 16 + f] = a1v;  // same-wave LDS RAW: in-order, no barrier
  // fused GEMM2: lane computes output cols 2f, 2f+1 for its node
  const float* ar = &arow[slot * 64];
  float s0 = 0.f, s1 = 0.f;
#pragma unroll
  for (int kk = 0; kk < 64; ++kk) {
    float a = ar[kk];                       // broadcast within 16-lane group
    float2 wv = ((const float2*)w2s)[kk * 16 + f];  // conflict-free
    s0 += a * wv.x; s1 += a * wv.y;
  }
  ((__half2*)h2s)[(size_t)d * 16 + f] = __floats2half2_rn(s0 * dv, s1 * dv);
}

// ---- gather layer 2: 4 nodes/wave (16 lanes x half2 = 32 feats), 16-deep ILP ----
__global__ __launch_bounds__(256) void gather32_kernel(
    const __half* __restrict__ h2s, const unsigned short* __restrict__ csr,
    const int* __restrict__ eoff, const int* __restrict__ ecnt,
    const float* __restrict__ dinv, const float* __restrict__ b2,
    float* __restrict__ out, int N) {
  int t = threadIdx.x;
  int d = blockIdx.x * 16 + (t >> 4);
  if (d >= N) return;
  int f2 = t & 15;  // half2 column (feats 2f2, 2f2+1)
  const __half2* h2p = (const __half2*)h2s;  // row stride 16 half2
  int beg = eoff[d], m = ecnt[d];
  float2 a0 = __half22float2(h2p[(size_t)d * 16 + f2]);  // self-loop
  float2 aA = make_float2(0.f, 0.f), aB = make_float2(0.f, 0.f), aC = make_float2(0.f, 0.f);
  int j = 0;
  for (; j + 16 <= m; j += 16) {
    int s_[16];
#pragma unroll
    for (int i = 0; i < 16; ++i) s_[i] = csr[beg + j + i];
    __half2 v_[16];
#pragma unroll
    for (int i = 0; i < 16; ++i) v_[i] = h2p[(size_t)s_[i] * 16 + f2];
#pragma unroll
    for (int i = 0; i < 16; ++i) {
      float2 f = __half22float2(v_[i]);
      float2* ac = (i & 3) == 0 ? &a0 : (i & 3) == 1 ? &aA : (i & 3) == 2 ? &aB : &aC;
      ac->x += f.x; ac->y += f.y;
    }
  }
  for (; j + 4 <= m; j += 4) {
    int s0 = csr[beg + j], s1 = csr[beg + j + 1], s2 = csr[beg + j + 2], s3 = csr[beg + j + 3];
    __half2 v0 = h2p[(size_t)s0 * 16 + f2], v1 = h2p[(size_t)s1 * 16 + f2];
    __half2 v2 = h2p[(size_t)s2 * 16 + f2], v3 = h2p[(size_t)s3 * 16 + f2];
    float2 f0 = __half22float2(v0), f1 = __half22float2(v1);
    float2 f2v = __half22float2(v2), f3 = __half22float2(v3);
    a0.x += f0.x; a0.y += f0.y; aA.x += f1.x; aA.y += f1.y;
    aB.x += f2v.x; aB.y += f2v.y; aC.x += f3.x; aC.y += f3.y;
  }
  for (; j < m; ++j) {
    float2 f = __half22float2(h2p[(size_t)csr[beg + j] * 16 + f2]);
    a0.x += f.x; a0.y += f.y;
  }
  float sx = (a0.x + aA.x) + (aB.x + aC.x);
  float sy = (a0.y + aA.y) + (aB.y + aC.y);
  float dv = dinv[d];
  float2 bb = ((const float2*)b2)[f2];
  ((float2*)out)[(size_t)d * 16 + f2] = make_float2(sx * dv + bb.x, sy * dv + bb.y);
}

extern "C" void kernel_launch(void* const* d_in, const int* in_sizes, int n_in,
                              void* d_out, int out_size, void* d_ws, size_t ws_size,
                              hipStream_t stream) {
  const float* x = (const float*)d_in[0];
  const int* edge_index = (const int*)d_in[1];
  // d_in[2] = edge_attr (unused by reference)
  const float* W1 = (const float*)d_in[3];
  const float* b1 = (const float*)d_in[4];
  const float* W2 = (const float*)d_in[5];
  const float* b2 = (const float*)d_in[6];
  float* out = (float*)d_out;

  const int N = in_sizes[0] / 128;  // 50000 (key packing requires <= 65536)
  const int E = in_sizes[1] / 2;    // 800000
  const int* src = edge_index;
  const int* dst = edge_index + E;

  const int B = (N + NPB - 1) >> SHIFT;     // 196 buckets
  const int nWG = (E + CHUNK - 1) / CHUNK;  // 196 blocks

  char* ws = (char*)d_ws;
  size_t off = 0;
  auto alloc = [&](size_t bytes) -> void* {
    void* p = ws + off;
    off += (bytes + 255) & ~(size_t)255;
    return p;
  };
  unsigned* keys = (unsigned*)alloc((size_t)E * 4);
  unsigned short* csr = (unsigned short*)alloc((size_t)E * 2);
  int* hist = (int*)alloc((size_t)B * nWG * 4);
  int* eoff = (int*)alloc((size_t)N * 4);
  int* ecnt = (int*)alloc((size_t)N * 4);
  float* dinv = (float*)alloc((size_t)N * 4);
  __half* h1s = (__half*)alloc((size_t)N * 64 * 2);
  __half* h2s = (__half*)alloc((size_t)N * 32 * 2);

  hist_kernel<<<nWG, 256, 0, stream>>>(dst, E, nWG, B, hist);
  scatterkeys_kernel<<<nWG, 256, 0, stream>>>(src, dst, E, nWG, B, hist, keys);
  bucket_build_kernel<<<B, 256, 0, stream>>>(keys, hist, nWG, B, N, csr, eoff, ecnt, dinv);
  gemm1_kernel<<<(N + 63) / 64, 256, 0, stream>>>(x, W1, dinv, h1s, N);
  gather64_gemm2_kernel<<<(N + 15) / 16, 256, 0, stream>>>(h1s, csr, eoff, ecnt, dinv, b1, W2, h2s, N);
  gather32_kernel<<<(N + 15) / 16, 256, 0, stream>>>(h2s, csr, eoff, ecnt, dinv, b2, out, N);
}

// Round 9
// 98.609 us; speedup vs baseline: 1.3059x; 1.3059x over previous
//
#include <hip/hip_runtime.h>
#include <hip/hip_fp16.h>
#include <cstdint>
#include <cstddef>

// 2-layer GCN. norm factorization: out[d] = dinv[d]*(h_s[d] + sum_{s->d} h_s[s]),
// h_s[i] = dinv[i]*(x@W)[i]. Self-loop folded in as the h_s[d] term.
// Deterministic 2-level counting sort -> ushort CSR -> per-node gather (fp16 rows,
// f32 accumulate). GEMM2 fused into the layer-1 gather epilogue. 7 kernels.

#define SHIFT 8                 // 256 nodes per coarse bucket
#define NPB 256
#define CHUNK 4096              // edges per histogram/scatter block
#define IMG_CAP 6144            // LDS csr-image capacity (avg bucket load ~4081)

// ---- K1: per-block bucket histogram. hist[b*nWG + w] = count of bucket b in block w ----
__global__ __launch_bounds__(256) void hist_kernel(const int* __restrict__ dst, int E, int nWG,
                                                   int B, int* __restrict__ hist) {
  __shared__ int h[256];
  int t = threadIdx.x, w = blockIdx.x;
  for (int i = t; i < B; i += 256) h[i] = 0;
  __syncthreads();
  int beg = w * CHUNK, end = min(beg + CHUNK, E);
  for (int i = beg + t; i < end; i += 256) atomicAdd(&h[dst[i] >> SHIFT], 1);
  __syncthreads();
  for (int i = t; i < B; i += 256) hist[i * nWG + w] = h[i];
}

// ---- K2: exclusive scan of each bucket row (over blocks); also row total ----
__global__ __launch_bounds__(256) void rowscan_kernel(const int* __restrict__ hist, int nWG,
                                                      int* __restrict__ rowscan, int* __restrict__ total) {
  int b = blockIdx.x, t = threadIdx.x;  // nWG <= 256
  int v = (t < nWG) ? hist[b * nWG + t] : 0;
  int lane = t & 63, wid = t >> 6;
  int x = v;
#pragma unroll
  for (int o = 1; o < 64; o <<= 1) { int y = __shfl_up(x, o, 64); if (lane >= o) x += y; }
  __shared__ int wsum[4];
  if (lane == 63) wsum[wid] = x;
  __syncthreads();
  int bw = 0;
  for (int i = 0; i < wid; ++i) bw += wsum[i];
  int incl = bw + x;
  if (t < nWG) rowscan[b * nWG + t] = incl - v;
  if (t == nWG - 1) total[b] = incl;
}

// ---- K3: LDS-staged scatter of packed keys (bucket<<24 | local<<16 | src) ----
__global__ __launch_bounds__(256) void scatterkeys_kernel(const int* __restrict__ src,
                                                          const int* __restrict__ dst, int E, int nWG,
                                                          int B, const int* __restrict__ hist,
                                                          const int* __restrict__ rowscan,
                                                          const int* __restrict__ total,
                                                          unsigned* __restrict__ keys) {
  __shared__ int loffs[256], cur[256], gb[256];
  __shared__ int wsum[4];
  __shared__ unsigned image[CHUNK];  // 16 KB
  int t = threadIdx.x, w = blockIdx.x;
  int lane = t & 63, wid = t >> 6;
  // in-block exclusive scan of total[] -> gb[b] = base[b] + rowscan[b][w]
  {
    int v = (t < B) ? total[t] : 0;
    int x = v;
#pragma unroll
    for (int o = 1; o < 64; o <<= 1) { int y = __shfl_up(x, o, 64); if (lane >= o) x += y; }
    if (lane == 63) wsum[wid] = x;
    __syncthreads();
    int bw = 0;
    for (int i = 0; i < wid; ++i) bw += wsum[i];
    int excl = bw + x - v;
    if (t < B) gb[t] = excl + rowscan[t * nWG + w];
  }
  __syncthreads();
  // local exclusive scan of this block's hist row -> loffs/cur
  {
    int v = (t < B) ? hist[t * nWG + w] : 0;
    int x = v;
#pragma unroll
    for (int o = 1; o < 64; o <<= 1) { int y = __shfl_up(x, o, 64); if (lane >= o) x += y; }
    if (lane == 63) wsum[wid] = x;
    __syncthreads();
    int bw = 0;
    for (int i = 0; i < wid; ++i) bw += wsum[i];
    int excl = bw + x - v;
    if (t < B) { loffs[t] = excl; cur[t] = excl; }
  }
  __syncthreads();
  // place into LDS image (position within block-local bucket run)
  int beg = w * CHUNK, end = min(beg + CHUNK, E);
  for (int i = beg + t; i < end; i += 256) {
    int d = dst[i], s = src[i];
    int b = d >> SHIFT;
    int p = atomicAdd(&cur[b], 1);
    image[p] = ((unsigned)b << 24) | ((unsigned)(d & (NPB - 1)) << 16) | (unsigned)s;
  }
  __syncthreads();
  // sequential write-out: dest = gb[b] + (i - loffs[b])
  int n = end - beg;
  for (int i = t; i < n; i += 256) {
    unsigned k = image[i];
    int b = (int)(k >> 24);
    keys[gb[b] + (i - loffs[b])] = k;
  }
}

// ---- K4: per-bucket: per-node counts -> eoff/ecnt/dinv; sort keys -> ushort csr ----
__global__ __launch_bounds__(256) void bucket_build_kernel(const unsigned* __restrict__ keys,
                                                           const int* __restrict__ total, int B, int N,
                                                           unsigned short* __restrict__ csr,
                                                           int* __restrict__ eoff,
                                                           int* __restrict__ ecnt,
                                                           float* __restrict__ dinv) {
  __shared__ int cnt[NPB], loffs[NPB], cur[NPB];
  __shared__ int red[4];
  __shared__ int image[IMG_CAP];
  int b = blockIdx.x, t = threadIdx.x;
  int lane = t & 63, wid = t >> 6;
  // gbeg = sum_{i<b} total[i] (in-block reduce, coalesced)
  int part = 0;
  for (int i = t; i < b; i += 256) part += total[i];
#pragma unroll
  for (int o = 32; o > 0; o >>= 1) part += __shfl_down(part, o, 64);
  if (lane == 0) red[wid] = part;
  __syncthreads();
  int gbeg = red[0] + red[1] + red[2] + red[3];
  int m = total[b];
  int gend = gbeg + m;
  int nb = b << SHIFT;
  int nn = min(NPB, N - nb);
  cnt[t] = 0;  // NPB == blockDim
  __syncthreads();
  for (int i = gbeg + t; i < gend; i += 256) atomicAdd(&cnt[(keys[i] >> 16) & 0xFF], 1);
  __syncthreads();
  if (t < 64) {  // 4-per-lane exclusive scan of cnt[0..255] in one wave
    int v0 = cnt[4 * t], v1 = cnt[4 * t + 1], v2 = cnt[4 * t + 2], v3 = cnt[4 * t + 3];
    int s = v0 + v1 + v2 + v3, x = s;
#pragma unroll
    for (int o = 1; o < 64; o <<= 1) { int y = __shfl_up(x, o, 64); if (t >= o) x += y; }
    int e = x - s;
    loffs[4 * t] = e;                 cur[4 * t] = e;
    loffs[4 * t + 1] = e + v0;        cur[4 * t + 1] = e + v0;
    loffs[4 * t + 2] = e + v0 + v1;   cur[4 * t + 2] = e + v0 + v1;
    loffs[4 * t + 3] = e + v0 + v1 + v2; cur[4 * t + 3] = e + v0 + v1 + v2;
  }
  __syncthreads();
  for (int n2 = t; n2 < nn; n2 += 256) {
    eoff[nb + n2] = gbeg + loffs[n2];
    ecnt[nb + n2] = cnt[n2];
    dinv[nb + n2] = 1.0f / sqrtf((float)(cnt[n2] + 1));  // +1 self-loop
  }
  if (m <= IMG_CAP) {
    for (int i = gbeg + t; i < gend; i += 256) {
      unsigned k = keys[i];
      int p = atomicAdd(&cur[(k >> 16) & 0xFF], 1);
      image[p] = (int)(k & 0xFFFFu);
    }
    __syncthreads();
    for (int i = t; i < m; i += 256) csr[gbeg + i] = (unsigned short)image[i];
  } else {  // statistically unreachable fallback
    for (int i = gbeg + t; i < gend; i += 256) {
      unsigned k = keys[i];
      int p = atomicAdd(&cur[(k >> 16) & 0xFF], 1);
      csr[gbeg + p] = (unsigned short)(k & 0xFFFFu);
    }
  }
}

// ---- GEMM1: h1s[i][c] = fp16( dinv[i] * (x @ W1)[i][c] )   (N x 128 @ 128 x 64) ----
__global__ __launch_bounds__(256) void gemm1_kernel(
    const float* __restrict__ x, const float* __restrict__ W1,
    const float* __restrict__ dinv, __half* __restrict__ h1s, int N) {
  __shared__ float ws[128 * 64];
  __shared__ float xs[64 * 128];
  const int t = threadIdx.x;
  const int rowBase = blockIdx.x * 64;
  float4* ws4 = (float4*)ws;
  float4* xs4 = (float4*)xs;
  for (int i = t; i < 128 * 16; i += 256) ws4[i] = ((const float4*)W1)[i];
  for (int i = t; i < 64 * 32; i += 256) {
    int r = i >> 5, kq = i & 31;
    int row = rowBase + r;
    float4 v = make_float4(0.f, 0.f, 0.f, 0.f);
    if (row < N) v = ((const float4*)x)[(size_t)row * 32 + kq];
    xs4[r * 32 + (kq ^ ((r >> 2) & 7))] = v;
  }
  __syncthreads();
  const int g = t & 15;
  const int rg = t >> 4;
  const int swz = rg & 7;
  float acc[4][4] = {};
  for (int kq = 0; kq < 32; ++kq) {
    float4 a[4];
#pragma unroll
    for (int j = 0; j < 4; ++j) a[j] = xs4[(4 * rg + j) * 32 + (kq ^ swz)];
    float4 w[4];
#pragma unroll
    for (int kk = 0; kk < 4; ++kk) w[kk] = ws4[(4 * kq + kk) * 16 + g];
#pragma unroll
    for (int j = 0; j < 4; ++j) {
      acc[j][0] += a[j].x * w[0].x + a[j].y * w[1].x + a[j].z * w[2].x + a[j].w * w[3].x;
      acc[j][1] += a[j].x * w[0].y + a[j].y * w[1].y + a[j].z * w[2].y + a[j].w * w[3].y;
      acc[j][2] += a[j].x * w[0].z + a[j].y * w[1].z + a[j].z * w[2].z + a[j].w * w[3].z;
      acc[j][3] += a[j].x * w[0].w + a[j].y * w[1].w + a[j].z * w[2].w + a[j].w * w[3].w;
    }
  }
#pragma unroll
  for (int j = 0; j < 4; ++j) {
    int row = rowBase + 4 * rg + j;
    if (row < N) {
      float dv = dinv[row];
      union { __half2 h2[2]; float2 f2v; } u;
      u.h2[0] = __floats2half2_rn(acc[j][0] * dv, acc[j][1] * dv);
      u.h2[1] = __floats2half2_rn(acc[j][2] * dv, acc[j][3] * dv);
      ((float2*)h1s)[(size_t)row * 16 + g] = u.f2v;
    }
  }
}

// ---- gather layer 1 + fused GEMM2 (round-6 proven structure, ushort csr) ----
// 2 nodes/wave (32 lanes x half2 = 64 feats), 16-deep ILP gather, f32 accumulate.
// Epilogue: a1 row -> LDS; h2s[d][c] = fp16( dinv[d] * (relu(acc*dinv+b1) @ W2)[c] ).
__global__ __launch_bounds__(256) void gather64_gemm2_kernel(
    const __half* __restrict__ h1s, const unsigned short* __restrict__ csr,
    const int* __restrict__ eoff, const int* __restrict__ ecnt,
    const float* __restrict__ dinv, const float* __restrict__ b1,
    const float* __restrict__ W2, __half* __restrict__ h2s, int N) {
  __shared__ float w2s[64 * 32];  // 8 KB, [k][c]
  __shared__ float arow[8 * 64];  // per-half-wave a1 row (8 nodes/block)
  int t = threadIdx.x;
  float4* w2s4 = (float4*)w2s;
  for (int i = t; i < 512; i += 256) w2s4[i] = ((const float4*)W2)[i];
  __syncthreads();  // all threads participate before any divergent exit
  int slot = t >> 5;                 // 0..7 node slot in block
  int d = blockIdx.x * 8 + slot;
  if (d >= N) return;
  int f2 = t & 31;                   // half2 column (feats 2f2, 2f2+1)
  const __half2* h1p = (const __half2*)h1s;  // row stride 32 half2
  int beg = eoff[d], m = ecnt[d];
  float2 a0 = __half22float2(h1p[(size_t)d * 32 + f2]);  // self-loop
  float2 aA = make_float2(0.f, 0.f), aB = make_float2(0.f, 0.f), aC = make_float2(0.f, 0.f);
  int j = 0;
  for (; j + 16 <= m; j += 16) {
    int s_[16];
#pragma unroll
    for (int i = 0; i < 16; ++i) s_[i] = csr[beg + j + i];
    __half2 v_[16];
#pragma unroll
    for (int i = 0; i < 16; ++i) v_[i] = h1p[(size_t)s_[i] * 32 + f2];
#pragma unroll
    for (int i = 0; i < 16; ++i) {
      float2 f = __half22float2(v_[i]);
      float2* ac = (i & 3) == 0 ? &a0 : (i & 3) == 1 ? &aA : (i & 3) == 2 ? &aB : &aC;
      ac->x += f.x; ac->y += f.y;
    }
  }
  for (; j + 4 <= m; j += 4) {
    int s0 = csr[beg + j], s1 = csr[beg + j + 1], s2 = csr[beg + j + 2], s3 = csr[beg + j + 3];
    __half2 v0 = h1p[(size_t)s0 * 32 + f2], v1 = h1p[(size_t)s1 * 32 + f2];
    __half2 v2 = h1p[(size_t)s2 * 32 + f2], v3 = h1p[(size_t)s3 * 32 + f2];
    float2 f0 = __half22float2(v0), f1 = __half22float2(v1);
    float2 f2v = __half22float2(v2), f3 = __half22float2(v3);
    a0.x += f0.x; a0.y += f0.y; aA.x += f1.x; aA.y += f1.y;
    aB.x += f2v.x; aB.y += f2v.y; aC.x += f3.x; aC.y += f3.y;
  }
  for (; j < m; ++j) {
    float2 f = __half22float2(h1p[(size_t)csr[beg + j] * 32 + f2]);
    a0.x += f.x; a0.y += f.y;
  }
  float sx = (a0.x + aA.x) + (aB.x + aC.x);
  float sy = (a0.y + aA.y) + (aB.y + aC.y);
  float dv = dinv[d];
  float2 bb = ((const float2*)b1)[f2];
  float ax = fmaxf(sx * dv + bb.x, 0.f);
  float ay = fmaxf(sy * dv + bb.y, 0.f);
  ((float2*)arow)[slot * 32 + f2] = make_float2(ax, ay);  // same-wave LDS RAW
  // fused GEMM2: lane computes output col c = f2 for its node
  const float* ar = &arow[slot * 64];
  float s = 0.f;
#pragma unroll
  for (int kk = 0; kk < 64; ++kk) s += ar[kk] * w2s[kk * 32 + f2];  // broadcast + 2-way alias
  h2s[(size_t)d * 32 + f2] = __float2half_rn(s * dv);
}

// ---- gather layer 2: 4 nodes/wave (16 lanes x half2 = 32 feats), 16-deep ILP ----
__global__ __launch_bounds__(256) void gather32_kernel(
    const __half* __restrict__ h2s, const unsigned short* __restrict__ csr,
    const int* __restrict__ eoff, const int* __restrict__ ecnt,
    const float* __restrict__ dinv, const float* __restrict__ b2,
    float* __restrict__ out, int N) {
  int t = threadIdx.x;
  int d = blockIdx.x * 16 + (t >> 4);
  if (d >= N) return;
  int f2 = t & 15;  // half2 column (feats 2f2, 2f2+1)
  const __half2* h2p = (const __half2*)h2s;  // row stride 16 half2
  int beg = eoff[d], m = ecnt[d];
  float2 a0 = __half22float2(h2p[(size_t)d * 16 + f2]);  // self-loop
  float2 aA = make_float2(0.f, 0.f), aB = make_float2(0.f, 0.f), aC = make_float2(0.f, 0.f);
  int j = 0;
  for (; j + 16 <= m; j += 16) {
    int s_[16];
#pragma unroll
    for (int i = 0; i < 16; ++i) s_[i] = csr[beg + j + i];
    __half2 v_[16];
#pragma unroll
    for (int i = 0; i < 16; ++i) v_[i] = h2p[(size_t)s_[i] * 16 + f2];
#pragma unroll
    for (int i = 0; i < 16; ++i) {
      float2 f = __half22float2(v_[i]);
      float2* ac = (i & 3) == 0 ? &a0 : (i & 3) == 1 ? &aA : (i & 3) == 2 ? &aB : &aC;
      ac->x += f.x; ac->y += f.y;
    }
  }
  for (; j + 4 <= m; j += 4) {
    int s0 = csr[beg + j], s1 = csr[beg + j + 1], s2 = csr[beg + j + 2], s3 = csr[beg + j + 3];
    __half2 v0 = h2p[(size_t)s0 * 16 + f2], v1 = h2p[(size_t)s1 * 16 + f2];
    __half2 v2 = h2p[(size_t)s2 * 16 + f2], v3 = h2p[(size_t)s3 * 16 + f2];
    float2 f0 = __half22float2(v0), f1 = __half22float2(v1);
    float2 f2v = __half22float2(v2), f3 = __half22float2(v3);
    a0.x += f0.x; a0.y += f0.y; aA.x += f1.x; aA.y += f1.y;
    aB.x += f2v.x; aB.y += f2v.y; aC.x += f3.x; aC.y += f3.y;
  }
  for (; j < m; ++j) {
    float2 f = __half22float2(h2p[(size_t)csr[beg + j] * 16 + f2]);
    a0.x += f.x; a0.y += f.y;
  }
  float sx = (a0.x + aA.x) + (aB.x + aC.x);
  float sy = (a0.y + aA.y) + (aB.y + aC.y);
  float dv = dinv[d];
  float2 bb = ((const float2*)b2)[f2];
  ((float2*)out)[(size_t)d * 16 + f2] = make_float2(sx * dv + bb.x, sy * dv + bb.y);
}

extern "C" void kernel_launch(void* const* d_in, const int* in_sizes, int n_in,
                              void* d_out, int out_size, void* d_ws, size_t ws_size,
                              hipStream_t stream) {
  const float* x = (const float*)d_in[0];
  const int* edge_index = (const int*)d_in[1];
  // d_in[2] = edge_attr (unused by reference)
  const float* W1 = (const float*)d_in[3];
  const float* b1 = (const float*)d_in[4];
  const float* W2 = (const float*)d_in[5];
  const float* b2 = (const float*)d_in[6];
  float* out = (float*)d_out;

  const int N = in_sizes[0] / 128;  // 50000 (key packing requires <= 65536)
  const int E = in_sizes[1] / 2;    // 800000
  const int* src = edge_index;
  const int* dst = edge_index + E;

  const int B = (N + NPB - 1) >> SHIFT;     // 196 buckets
  const int nWG = (E + CHUNK - 1) / CHUNK;  // 196 blocks

  char* ws = (char*)d_ws;
  size_t off = 0;
  auto alloc = [&](size_t bytes) -> void* {
    void* p = ws + off;
    off += (bytes + 255) & ~(size_t)255;
    return p;
  };
  unsigned* keys = (unsigned*)alloc((size_t)E * 4);
  unsigned short* csr = (unsigned short*)alloc((size_t)E * 2);
  int* hist = (int*)alloc((size_t)B * nWG * 4);
  int* rowscan = (int*)alloc((size_t)B * nWG * 4);
  int* total = (int*)alloc((size_t)B * 4);
  int* eoff = (int*)alloc((size_t)N * 4);
  int* ecnt = (int*)alloc((size_t)N * 4);
  float* dinv = (float*)alloc((size_t)N * 4);
  __half* h1s = (__half*)alloc((size_t)N * 64 * 2);
  __half* h2s = (__half*)alloc((size_t)N * 32 * 2);

  hist_kernel<<<nWG, 256, 0, stream>>>(dst, E, nWG, B, hist);
  rowscan_kernel<<<B, 256, 0, stream>>>(hist, nWG, rowscan, total);
  scatterkeys_kernel<<<nWG, 256, 0, stream>>>(src, dst, E, nWG, B, hist, rowscan, total, keys);
  bucket_build_kernel<<<B, 256, 0, stream>>>(keys, total, B, N, csr, eoff, ecnt, dinv);
  gemm1_kernel<<<(N + 63) / 64, 256, 0, stream>>>(x, W1, dinv, h1s, N);
  gather64_gemm2_kernel<<<(N + 7) / 8, 256, 0, stream>>>(h1s, csr, eoff, ecnt, dinv, b1, W2, h2s, N);
  gather32_kernel<<<(N + 15) / 16, 256, 0, stream>>>(h2s, csr, eoff, ecnt, dinv, b2, out, N);
}

// Round 10
// 90.894 us; speedup vs baseline: 1.4167x; 1.0849x over previous
//
#include <hip/hip_runtime.h>
#include <hip/hip_fp16.h>
#include <cstdint>
#include <cstddef>

// 2-layer GCN. norm factorization: out[d] = dinv[d]*(h_s[d] + sum_{s->d} h_s[s]),
// h_s[i] = dinv[i]*(x@W)[i]. Self-loop folded in as the h_s[d] term.
// Single-pass LDS bucket sort with global atomic region reservation (fixed-capacity
// bucket regions) -> ushort CSR -> per-node gather (fp16 rows, f32 accumulate).
// GEMM2 fused into the layer-1 gather epilogue. 5 kernels + 1 memset.

#define SHIFT 8                 // 256 nodes per coarse bucket
#define NPB 256
#define CHUNK 4096              // edges per scatter block
#define CAP 8192                // per-bucket key/csr region capacity (avg load ~4081)
#define CAPSHIFT 13
#define IMG_CAP 6144            // LDS csr-image capacity in bucket_build

// ---- K1: per-chunk LDS bucket sort + atomic region reservation + coalesced writeout ----
__global__ __launch_bounds__(256) void scatter_local_kernel(
    const int* __restrict__ src, const int* __restrict__ dst, int E, int B,
    int* __restrict__ gcur, unsigned* __restrict__ keys) {
  __shared__ int loffs[256], cur[256], gb[256];
  __shared__ int wsum[4];
  __shared__ unsigned image[CHUNK];  // 16 KB
  int t = threadIdx.x, w = blockIdx.x;
  int lane = t & 63, wid = t >> 6;
  cur[t] = 0;
  __syncthreads();
  int beg = w * CHUNK, end = min(beg + CHUNK, E);
  for (int i = beg + t; i < end; i += 256) atomicAdd(&cur[dst[i] >> SHIFT], 1);
  __syncthreads();
  // exclusive scan of per-bucket counts -> loffs; cur reset to running cursor
  {
    int v = cur[t];
    int x = v;
#pragma unroll
    for (int o = 1; o < 64; o <<= 1) { int y = __shfl_up(x, o, 64); if (lane >= o) x += y; }
    if (lane == 63) wsum[wid] = x;
    __syncthreads();
    int bw = 0;
    for (int i = 0; i < wid; ++i) bw += wsum[i];
    int excl = bw + x - v;
    loffs[t] = excl;
    cur[t] = excl;
  }
  __syncthreads();
  // place into LDS image (bucket<<24 | local<<16 | src)
  for (int i = beg + t; i < end; i += 256) {
    int d = dst[i], s = src[i];
    int b = d >> SHIFT;
    int p = atomicAdd(&cur[b], 1);
    image[p] = ((unsigned)b << 24) | ((unsigned)(d & (NPB - 1)) << 16) | (unsigned)s;
  }
  __syncthreads();
  // reserve space in each bucket's global region
  if (t < B) {
    int c = cur[t] - loffs[t];
    gb[t] = (c > 0) ? atomicAdd(&gcur[t], c) : 0;
  }
  __syncthreads();
  // coalesced writeout: dest = bucket region + reserved base + run position
  int n = end - beg;
  for (int i = t; i < n; i += 256) {
    unsigned k = image[i];
    int b = (int)(k >> 24);
    int pos = gb[b] + (i - loffs[b]);
    if (pos < CAP) keys[((size_t)b << CAPSHIFT) + pos] = k;
  }
}

// ---- K2: per-bucket: per-node counts -> eoff/ecnt/dinv; sort keys -> ushort csr ----
__global__ __launch_bounds__(256) void bucket_build_kernel(const unsigned* __restrict__ keys,
                                                           const int* __restrict__ gcur, int N,
                                                           unsigned short* __restrict__ csr,
                                                           int* __restrict__ eoff,
                                                           int* __restrict__ ecnt,
                                                           float* __restrict__ dinv) {
  __shared__ int cnt[NPB], loffs[NPB], cur[NPB];
  __shared__ int image[IMG_CAP];
  int b = blockIdx.x, t = threadIdx.x;
  int m = min(gcur[b], CAP);
  size_t kbase = (size_t)b << CAPSHIFT;
  int nb = b << SHIFT;
  int nn = min(NPB, N - nb);
  cnt[t] = 0;  // NPB == blockDim
  __syncthreads();
  for (int i = t; i < m; i += 256) atomicAdd(&cnt[(keys[kbase + i] >> 16) & 0xFF], 1);
  __syncthreads();
  if (t < 64) {  // 4-per-lane exclusive scan of cnt[0..255] in one wave
    int v0 = cnt[4 * t], v1 = cnt[4 * t + 1], v2 = cnt[4 * t + 2], v3 = cnt[4 * t + 3];
    int s = v0 + v1 + v2 + v3, x = s;
#pragma unroll
    for (int o = 1; o < 64; o <<= 1) { int y = __shfl_up(x, o, 64); if (t >= o) x += y; }
    int e = x - s;
    loffs[4 * t] = e;                 cur[4 * t] = e;
    loffs[4 * t + 1] = e + v0;        cur[4 * t + 1] = e + v0;
    loffs[4 * t + 2] = e + v0 + v1;   cur[4 * t + 2] = e + v0 + v1;
    loffs[4 * t + 3] = e + v0 + v1 + v2; cur[4 * t + 3] = e + v0 + v1 + v2;
  }
  __syncthreads();
  for (int n2 = t; n2 < nn; n2 += 256) {
    eoff[nb + n2] = (int)kbase + loffs[n2];
    ecnt[nb + n2] = cnt[n2];
    dinv[nb + n2] = 1.0f / sqrtf((float)(cnt[n2] + 1));  // +1 self-loop
  }
  if (m <= IMG_CAP) {
    for (int i = t; i < m; i += 256) {
      unsigned k = keys[kbase + i];
      int p = atomicAdd(&cur[(k >> 16) & 0xFF], 1);
      image[p] = (int)(k & 0xFFFFu);
    }
    __syncthreads();
    for (int i = t; i < m; i += 256) csr[kbase + i] = (unsigned short)image[i];
  } else {  // statistically unreachable fallback
    for (int i = t; i < m; i += 256) {
      unsigned k = keys[kbase + i];
      int p = atomicAdd(&cur[(k >> 16) & 0xFF], 1);
      csr[kbase + p] = (unsigned short)(k & 0xFFFFu);
    }
  }
}

// ---- GEMM1: h1s[i][c] = fp16( dinv[i] * (x @ W1)[i][c] )   (N x 128 @ 128 x 64) ----
__global__ __launch_bounds__(256) void gemm1_kernel(
    const float* __restrict__ x, const float* __restrict__ W1,
    const float* __restrict__ dinv, __half* __restrict__ h1s, int N) {
  __shared__ float ws[128 * 64];
  __shared__ float xs[64 * 128];
  const int t = threadIdx.x;
  const int rowBase = blockIdx.x * 64;
  float4* ws4 = (float4*)ws;
  float4* xs4 = (float4*)xs;
  for (int i = t; i < 128 * 16; i += 256) ws4[i] = ((const float4*)W1)[i];
  for (int i = t; i < 64 * 32; i += 256) {
    int r = i >> 5, kq = i & 31;
    int row = rowBase + r;
    float4 v = make_float4(0.f, 0.f, 0.f, 0.f);
    if (row < N) v = ((const float4*)x)[(size_t)row * 32 + kq];
    xs4[r * 32 + (kq ^ ((r >> 2) & 7))] = v;
  }
  __syncthreads();
  const int g = t & 15;
  const int rg = t >> 4;
  const int swz = rg & 7;
  float acc[4][4] = {};
  for (int kq = 0; kq < 32; ++kq) {
    float4 a[4];
#pragma unroll
    for (int j = 0; j < 4; ++j) a[j] = xs4[(4 * rg + j) * 32 + (kq ^ swz)];
    float4 w[4];
#pragma unroll
    for (int kk = 0; kk < 4; ++kk) w[kk] = ws4[(4 * kq + kk) * 16 + g];
#pragma unroll
    for (int j = 0; j < 4; ++j) {
      acc[j][0] += a[j].x * w[0].x + a[j].y * w[1].x + a[j].z * w[2].x + a[j].w * w[3].x;
      acc[j][1] += a[j].x * w[0].y + a[j].y * w[1].y + a[j].z * w[2].y + a[j].w * w[3].y;
      acc[j][2] += a[j].x * w[0].z + a[j].y * w[1].z + a[j].z * w[2].z + a[j].w * w[3].z;
      acc[j][3] += a[j].x * w[0].w + a[j].y * w[1].w + a[j].z * w[2].w + a[j].w * w[3].w;
    }
  }
#pragma unroll
  for (int j = 0; j < 4; ++j) {
    int row = rowBase + 4 * rg + j;
    if (row < N) {
      float dv = dinv[row];
      union { __half2 h2[2]; float2 f2v; } u;
      u.h2[0] = __floats2half2_rn(acc[j][0] * dv, acc[j][1] * dv);
      u.h2[1] = __floats2half2_rn(acc[j][2] * dv, acc[j][3] * dv);
      ((float2*)h1s)[(size_t)row * 16 + g] = u.f2v;
    }
  }
}

// ---- gather layer 1 + fused GEMM2 ----
// 2 nodes/wave (32 lanes x half2 = 64 feats), 16-batch + masked-16 tail, f32 accum.
// Epilogue: a1 row -> LDS; h2s[d][c] = fp16( dinv[d] * (relu(acc*dinv+b1) @ W2)[c] ).
__global__ __launch_bounds__(256) void gather64_gemm2_kernel(
    const __half* __restrict__ h1s, const unsigned short* __restrict__ csr,
    const int* __restrict__ eoff, const int* __restrict__ ecnt,
    const float* __restrict__ dinv, const float* __restrict__ b1,
    const float* __restrict__ W2, __half* __restrict__ h2s, int N) {
  __shared__ float w2s[64 * 32];  // 8 KB, [k][c]
  __shared__ float arow[8 * 64];  // per-half-wave a1 row (8 nodes/block)
  int t = threadIdx.x;
  float4* w2s4 = (float4*)w2s;
  for (int i = t; i < 512; i += 256) w2s4[i] = ((const float4*)W2)[i];
  __syncthreads();  // all threads participate before any divergent exit
  int slot = t >> 5;                 // 0..7 node slot in block
  int d = blockIdx.x * 8 + slot;
  if (d >= N) return;
  int f2 = t & 31;                   // half2 column (feats 2f2, 2f2+1)
  const __half2* h1p = (const __half2*)h1s;  // row stride 32 half2
  int beg = eoff[d], m = ecnt[d];
  float2 a0 = __half22float2(h1p[(size_t)d * 32 + f2]);  // self-loop
  float2 aA = make_float2(0.f, 0.f), aB = make_float2(0.f, 0.f), aC = make_float2(0.f, 0.f);
  int j = 0;
  for (; j + 16 <= m; j += 16) {
    int s_[16];
#pragma unroll
    for (int i = 0; i < 16; ++i) s_[i] = csr[beg + j + i];
    __half2 v_[16];
#pragma unroll
    for (int i = 0; i < 16; ++i) v_[i] = h1p[(size_t)s_[i] * 32 + f2];
#pragma unroll
    for (int i = 0; i < 16; ++i) {
      float2 f = __half22float2(v_[i]);
      float2* ac = (i & 3) == 0 ? &a0 : (i & 3) == 1 ? &aA : (i & 3) == 2 ? &aB : &aC;
      ac->x += f.x; ac->y += f.y;
    }
  }
  if (j < m) {  // masked 16-batch tail: single dependent round
    int s_[16];
#pragma unroll
    for (int i = 0; i < 16; ++i) { int jj = j + i; s_[i] = csr[beg + (jj < m ? jj : m - 1)]; }
    __half2 v_[16];
#pragma unroll
    for (int i = 0; i < 16; ++i) v_[i] = h1p[(size_t)s_[i] * 32 + f2];
#pragma unroll
    for (int i = 0; i < 16; ++i) {
      float2 f = __half22float2(v_[i]);
      bool ok = (j + i < m);
      float2* ac = (i & 3) == 0 ? &a0 : (i & 3) == 1 ? &aA : (i & 3) == 2 ? &aB : &aC;
      ac->x += ok ? f.x : 0.f; ac->y += ok ? f.y : 0.f;
    }
  }
  float sx = (a0.x + aA.x) + (aB.x + aC.x);
  float sy = (a0.y + aA.y) + (aB.y + aC.y);
  float dv = dinv[d];
  float2 bb = ((const float2*)b1)[f2];
  float ax = fmaxf(sx * dv + bb.x, 0.f);
  float ay = fmaxf(sy * dv + bb.y, 0.f);
  ((float2*)arow)[slot * 32 + f2] = make_float2(ax, ay);  // same-wave LDS RAW
  // fused GEMM2: lane computes output col c = f2 for its node
  const float* ar = &arow[slot * 64];
  float s = 0.f;
#pragma unroll
  for (int kk = 0; kk < 64; ++kk) s += ar[kk] * w2s[kk * 32 + f2];  // broadcast + 2-way alias
  h2s[(size_t)d * 32 + f2] = __float2half_rn(s * dv);
}

// ---- gather layer 2: 4 nodes/wave (16 lanes x half2 = 32 feats) ----
__global__ __launch_bounds__(256) void gather32_kernel(
    const __half* __restrict__ h2s, const unsigned short* __restrict__ csr,
    const int* __restrict__ eoff, const int* __restrict__ ecnt,
    const float* __restrict__ dinv, const float* __restrict__ b2,
    float* __restrict__ out, int N) {
  int t = threadIdx.x;
  int d = blockIdx.x * 16 + (t >> 4);
  if (d >= N) return;
  int f2 = t & 15;  // half2 column (feats 2f2, 2f2+1)
  const __half2* h2p = (const __half2*)h2s;  // row stride 16 half2
  int beg = eoff[d], m = ecnt[d];
  float2 a0 = __half22float2(h2p[(size_t)d * 16 + f2]);  // self-loop
  float2 aA = make_float2(0.f, 0.f), aB = make_float2(0.f, 0.f), aC = make_float2(0.f, 0.f);
  int j = 0;
  for (; j + 16 <= m; j += 16) {
    int s_[16];
#pragma unroll
    for (int i = 0; i < 16; ++i) s_[i] = csr[beg + j + i];
    __half2 v_[16];
#pragma unroll
    for (int i = 0; i < 16; ++i) v_[i] = h2p[(size_t)s_[i] * 16 + f2];
#pragma unroll
    for (int i = 0; i < 16; ++i) {
      float2 f = __half22float2(v_[i]);
      float2* ac = (i & 3) == 0 ? &a0 : (i & 3) == 1 ? &aA : (i & 3) == 2 ? &aB : &aC;
      ac->x += f.x; ac->y += f.y;
    }
  }
  if (j < m) {  // masked 16-batch tail
    int s_[16];
#pragma unroll
    for (int i = 0; i < 16; ++i) { int jj = j + i; s_[i] = csr[beg + (jj < m ? jj : m - 1)]; }
    __half2 v_[16];
#pragma unroll
    for (int i = 0; i < 16; ++i) v_[i] = h2p[(size_t)s_[i] * 16 + f2];
#pragma unroll
    for (int i = 0; i < 16; ++i) {
      float2 f = __half22float2(v_[i]);
      bool ok = (j + i < m);
      float2* ac = (i & 3) == 0 ? &a0 : (i & 3) == 1 ? &aA : (i & 3) == 2 ? &aB : &aC;
      ac->x += ok ? f.x : 0.f; ac->y += ok ? f.y : 0.f;
    }
  }
  float sx = (a0.x + aA.x) + (aB.x + aC.x);
  float sy = (a0.y + aA.y) + (aB.y + aC.y);
  float dv = dinv[d];
  float2 bb = ((const float2*)b2)[f2];
  ((float2*)out)[(size_t)d * 16 + f2] = make_float2(sx * dv + bb.x, sy * dv + bb.y);
}

extern "C" void kernel_launch(void* const* d_in, const int* in_sizes, int n_in,
                              void* d_out, int out_size, void* d_ws, size_t ws_size,
                              hipStream_t stream) {
  const float* x = (const float*)d_in[0];
  const int* edge_index = (const int*)d_in[1];
  // d_in[2] = edge_attr (unused by reference)
  const float* W1 = (const float*)d_in[3];
  const float* b1 = (const float*)d_in[4];
  const float* W2 = (const float*)d_in[5];
  const float* b2 = (const float*)d_in[6];
  float* out = (float*)d_out;

  const int N = in_sizes[0] / 128;  // 50000 (key packing requires <= 65536)
  const int E = in_sizes[1] / 2;    // 800000
  const int* src = edge_index;
  const int* dst = edge_index + E;

  const int B = (N + NPB - 1) >> SHIFT;     // 196 buckets
  const int nWG = (E + CHUNK - 1) / CHUNK;  // 196 blocks

  char* ws = (char*)d_ws;
  size_t off = 0;
  auto alloc = [&](size_t bytes) -> void* {
    void* p = ws + off;
    off += (bytes + 255) & ~(size_t)255;
    return p;
  };
  unsigned* keys = (unsigned*)alloc((size_t)B * CAP * 4);        // padded bucket regions
  unsigned short* csr = (unsigned short*)alloc((size_t)B * CAP * 2);
  int* gcur = (int*)alloc((size_t)B * 4);
  int* eoff = (int*)alloc((size_t)N * 4);
  int* ecnt = (int*)alloc((size_t)N * 4);
  float* dinv = (float*)alloc((size_t)N * 4);
  __half* h1s = (__half*)alloc((size_t)N * 64 * 2);
  __half* h2s = (__half*)alloc((size_t)N * 32 * 2);

  hipMemsetAsync(gcur, 0, (size_t)B * 4, stream);
  scatter_local_kernel<<<nWG, 256, 0, stream>>>(src, dst, E, B, gcur, keys);
  bucket_build_kernel<<<B, 256, 0, stream>>>(keys, gcur, N, csr, eoff, ecnt, dinv);
  gemm1_kernel<<<(N + 63) / 64, 256, 0, stream>>>(x, W1, dinv, h1s, N);
  gather64_gemm2_kernel<<<(N + 7) / 8, 256, 0, stream>>>(h1s, csr, eoff, ecnt, dinv, b1, W2, h2s, N);
  gather32_kernel<<<(N + 15) / 16, 256, 0, stream>>>(h2s, csr, eoff, ecnt, dinv, b2, out, N);
}

// Round 11
// 90.344 us; speedup vs baseline: 1.4254x; 1.0061x over previous
//
#include <hip/hip_runtime.h>
#include <hip/hip_fp16.h>
#include <cstdint>
#include <cstddef>

// 2-layer GCN. norm factorization: out[d] = dinv[d]*(h_s[d] + sum_{s->d} h_s[s]),
// h_s[i] = dinv[i]*(x@W)[i]. Self-loop folded in as the h_s[d] term.
// Single-pass LDS bucket sort with global atomic region reservation -> ushort CSR
// -> per-node gather (fp16 rows, f32 accumulate, narrow lane-groups: 16-lane/node L1,
// 8-lane/node L2 -> 4/8 edges per vmem instruction). GEMM2 fused into gather-L1
// epilogue with bank-padded arow. 5 kernels + 1 memset.

#define SHIFT 8                 // 256 nodes per coarse bucket
#define NPB 256
#define CHUNK 4096              // edges per scatter block
#define CAP 8192                // per-bucket key/csr region capacity (avg load ~4081)
#define CAPSHIFT 13
#define IMG_CAP 6144            // LDS csr-image capacity in bucket_build

// ---- K1: per-chunk LDS bucket sort + atomic region reservation + coalesced writeout ----
__global__ __launch_bounds__(256) void scatter_local_kernel(
    const int* __restrict__ src, const int* __restrict__ dst, int E, int B,
    int* __restrict__ gcur, unsigned* __restrict__ keys) {
  __shared__ int loffs[256], cur[256], gb[256];
  __shared__ int wsum[4];
  __shared__ unsigned image[CHUNK];  // 16 KB
  int t = threadIdx.x, w = blockIdx.x;
  int lane = t & 63, wid = t >> 6;
  cur[t] = 0;
  __syncthreads();
  int beg = w * CHUNK, end = min(beg + CHUNK, E);
  for (int i = beg + t; i < end; i += 256) atomicAdd(&cur[dst[i] >> SHIFT], 1);
  __syncthreads();
  // exclusive scan of per-bucket counts -> loffs; cur reset to running cursor
  {
    int v = cur[t];
    int x = v;
#pragma unroll
    for (int o = 1; o < 64; o <<= 1) { int y = __shfl_up(x, o, 64); if (lane >= o) x += y; }
    if (lane == 63) wsum[wid] = x;
    __syncthreads();
    int bw = 0;
    for (int i = 0; i < wid; ++i) bw += wsum[i];
    int excl = bw + x - v;
    loffs[t] = excl;
    cur[t] = excl;
  }
  __syncthreads();
  // place into LDS image (bucket<<24 | local<<16 | src)
  for (int i = beg + t; i < end; i += 256) {
    int d = dst[i], s = src[i];
    int b = d >> SHIFT;
    int p = atomicAdd(&cur[b], 1);
    image[p] = ((unsigned)b << 24) | ((unsigned)(d & (NPB - 1)) << 16) | (unsigned)s;
  }
  __syncthreads();
  // reserve space in each bucket's global region
  if (t < B) {
    int c = cur[t] - loffs[t];
    gb[t] = (c > 0) ? atomicAdd(&gcur[t], c) : 0;
  }
  __syncthreads();
  // coalesced writeout: dest = bucket region + reserved base + run position
  int n = end - beg;
  for (int i = t; i < n; i += 256) {
    unsigned k = image[i];
    int b = (int)(k >> 24);
    int pos = gb[b] + (i - loffs[b]);
    if (pos < CAP) keys[((size_t)b << CAPSHIFT) + pos] = k;
  }
}

// ---- K2: per-bucket: per-node counts -> eoff/ecnt/dinv; sort keys -> ushort csr ----
__global__ __launch_bounds__(256) void bucket_build_kernel(const unsigned* __restrict__ keys,
                                                           const int* __restrict__ gcur, int N,
                                                           unsigned short* __restrict__ csr,
                                                           int* __restrict__ eoff,
                                                           int* __restrict__ ecnt,
                                                           float* __restrict__ dinv) {
  __shared__ int cnt[NPB], loffs[NPB], cur[NPB];
  __shared__ int image[IMG_CAP];
  int b = blockIdx.x, t = threadIdx.x;
  int m = min(gcur[b], CAP);
  size_t kbase = (size_t)b << CAPSHIFT;
  int nb = b << SHIFT;
  int nn = min(NPB, N - nb);
  cnt[t] = 0;  // NPB == blockDim
  __syncthreads();
  for (int i = t; i < m; i += 256) atomicAdd(&cnt[(keys[kbase + i] >> 16) & 0xFF], 1);
  __syncthreads();
  if (t < 64) {  // 4-per-lane exclusive scan of cnt[0..255] in one wave
    int v0 = cnt[4 * t], v1 = cnt[4 * t + 1], v2 = cnt[4 * t + 2], v3 = cnt[4 * t + 3];
    int s = v0 + v1 + v2 + v3, x = s;
#pragma unroll
    for (int o = 1; o < 64; o <<= 1) { int y = __shfl_up(x, o, 64); if (t >= o) x += y; }
    int e = x - s;
    loffs[4 * t] = e;                 cur[4 * t] = e;
    loffs[4 * t + 1] = e + v0;        cur[4 * t + 1] = e + v0;
    loffs[4 * t + 2] = e + v0 + v1;   cur[4 * t + 2] = e + v0 + v1;
    loffs[4 * t + 3] = e + v0 + v1 + v2; cur[4 * t + 3] = e + v0 + v1 + v2;
  }
  __syncthreads();
  for (int n2 = t; n2 < nn; n2 += 256) {
    eoff[nb + n2] = (int)kbase + loffs[n2];
    ecnt[nb + n2] = cnt[n2];
    dinv[nb + n2] = 1.0f / sqrtf((float)(cnt[n2] + 1));  // +1 self-loop
  }
  if (m <= IMG_CAP) {
    for (int i = t; i < m; i += 256) {
      unsigned k = keys[kbase + i];
      int p = atomicAdd(&cur[(k >> 16) & 0xFF], 1);
      image[p] = (int)(k & 0xFFFFu);
    }
    __syncthreads();
    for (int i = t; i < m; i += 256) csr[kbase + i] = (unsigned short)image[i];
  } else {  // statistically unreachable fallback
    for (int i = t; i < m; i += 256) {
      unsigned k = keys[kbase + i];
      int p = atomicAdd(&cur[(k >> 16) & 0xFF], 1);
      csr[kbase + p] = (unsigned short)(k & 0xFFFFu);
    }
  }
}

// ---- GEMM1: h1s[i][c] = fp16( dinv[i] * (x @ W1)[i][c] )   (N x 128 @ 128 x 64) ----
__global__ __launch_bounds__(256) void gemm1_kernel(
    const float* __restrict__ x, const float* __restrict__ W1,
    const float* __restrict__ dinv, __half* __restrict__ h1s, int N) {
  __shared__ float ws[128 * 64];
  __shared__ float xs[64 * 128];
  const int t = threadIdx.x;
  const int rowBase = blockIdx.x * 64;
  float4* ws4 = (float4*)ws;
  float4* xs4 = (float4*)xs;
  for (int i = t; i < 128 * 16; i += 256) ws4[i] = ((const float4*)W1)[i];
  for (int i = t; i < 64 * 32; i += 256) {
    int r = i >> 5, kq = i & 31;
    int row = rowBase + r;
    float4 v = make_float4(0.f, 0.f, 0.f, 0.f);
    if (row < N) v = ((const float4*)x)[(size_t)row * 32 + kq];
    xs4[r * 32 + (kq ^ ((r >> 2) & 7))] = v;
  }
  __syncthreads();
  const int g = t & 15;
  const int rg = t >> 4;
  const int swz = rg & 7;
  float acc[4][4] = {};
  for (int kq = 0; kq < 32; ++kq) {
    float4 a[4];
#pragma unroll
    for (int j = 0; j < 4; ++j) a[j] = xs4[(4 * rg + j) * 32 + (kq ^ swz)];
    float4 w[4];
#pragma unroll
    for (int kk = 0; kk < 4; ++kk) w[kk] = ws4[(4 * kq + kk) * 16 + g];
#pragma unroll
    for (int j = 0; j < 4; ++j) {
      acc[j][0] += a[j].x * w[0].x + a[j].y * w[1].x + a[j].z * w[2].x + a[j].w * w[3].x;
      acc[j][1] += a[j].x * w[0].y + a[j].y * w[1].y + a[j].z * w[2].y + a[j].w * w[3].y;
      acc[j][2] += a[j].x * w[0].z + a[j].y * w[1].z + a[j].z * w[2].z + a[j].w * w[3].z;
      acc[j][3] += a[j].x * w[0].w + a[j].y * w[1].w + a[j].z * w[2].w + a[j].w * w[3].w;
    }
  }
#pragma unroll
  for (int j = 0; j < 4; ++j) {
    int row = rowBase + 4 * rg + j;
    if (row < N) {
      float dv = dinv[row];
      union { __half2 h2[2]; float2 f2v; } u;
      u.h2[0] = __floats2half2_rn(acc[j][0] * dv, acc[j][1] * dv);
      u.h2[1] = __floats2half2_rn(acc[j][2] * dv, acc[j][3] * dv);
      ((float2*)h1s)[(size_t)row * 16 + g] = u.f2v;
    }
  }
}

__device__ __forceinline__ float4 unpack4(float2 raw) {
  union { float2 f2v; __half2 h2[2]; } u; u.f2v = raw;
  float2 lo = __half22float2(u.h2[0]), hi = __half22float2(u.h2[1]);
  return make_float4(lo.x, lo.y, hi.x, hi.y);
}
__device__ __forceinline__ void acc4(float4& a, const float4& v) {
  a.x += v.x; a.y += v.y; a.z += v.z; a.w += v.w;
}

// ---- gather layer 1 + fused GEMM2 ----
// 16 lanes/node (lane = float2 = 4 halves), 16 nodes/block -> 4 edges per vmem instr.
// 16-batch + masked-16 tail, f32 accumulate. Epilogue: a1 row -> bank-padded LDS;
// h2s[d][c] = fp16( dinv[d] * (relu(agg*dinv+b1) @ W2)[c] ), lane computes 2 cols.
__global__ __launch_bounds__(256) void gather64_gemm2_kernel(
    const __half* __restrict__ h1s, const unsigned short* __restrict__ csr,
    const int* __restrict__ eoff, const int* __restrict__ ecnt,
    const float* __restrict__ dinv, const float* __restrict__ b1,
    const float* __restrict__ W2, __half* __restrict__ h2s, int N) {
  __shared__ float w2s[64 * 32];   // 8 KB, [k][c]
  __shared__ float arow[16 * 68];  // stride 68: wave's 4 slots land on distinct banks
  int t = threadIdx.x;
  float4* w2s4 = (float4*)w2s;
  for (int i = t; i < 512; i += 256) w2s4[i] = ((const float4*)W2)[i];
  __syncthreads();  // all threads participate before any divergent exit
  int slot = t >> 4;               // 0..15 node slot in block
  int d = blockIdx.x * 16 + slot;
  if (d >= N) return;
  int f = t & 15;                  // float2 column: halves 4f..4f+3
  const float2* h1p = (const float2*)h1s;  // row stride 16 float2
  int beg = eoff[d], m = ecnt[d];
  float4 a0 = unpack4(h1p[(size_t)d * 16 + f]);  // self-loop
  float4 aA = make_float4(0.f, 0.f, 0.f, 0.f);
  float4 aB = make_float4(0.f, 0.f, 0.f, 0.f);
  float4 aC = make_float4(0.f, 0.f, 0.f, 0.f);
  int j = 0;
  for (; j + 16 <= m; j += 16) {
    int s_[16];
#pragma unroll
    for (int i = 0; i < 16; ++i) s_[i] = csr[beg + j + i];
    float2 v_[16];
#pragma unroll
    for (int i = 0; i < 16; ++i) v_[i] = h1p[(size_t)s_[i] * 16 + f];
#pragma unroll
    for (int i = 0; i < 16; ++i) {
      float4 v = unpack4(v_[i]);
      float4* ac = (i & 3) == 0 ? &a0 : (i & 3) == 1 ? &aA : (i & 3) == 2 ? &aB : &aC;
      acc4(*ac, v);
    }
  }
  if (j < m) {  // masked 16-batch tail: single dependent round
    int s_[16];
#pragma unroll
    for (int i = 0; i < 16; ++i) { int jj = j + i; s_[i] = csr[beg + (jj < m ? jj : m - 1)]; }
    float2 v_[16];
#pragma unroll
    for (int i = 0; i < 16; ++i) v_[i] = h1p[(size_t)s_[i] * 16 + f];
#pragma unroll
    for (int i = 0; i < 16; ++i) {
      float4 v = unpack4(v_[i]);
      bool ok = (j + i < m);
      float4 vm = make_float4(ok ? v.x : 0.f, ok ? v.y : 0.f, ok ? v.z : 0.f, ok ? v.w : 0.f);
      float4* ac = (i & 3) == 0 ? &a0 : (i & 3) == 1 ? &aA : (i & 3) == 2 ? &aB : &aC;
      acc4(*ac, vm);
    }
  }
  float g0 = (a0.x + aA.x) + (aB.x + aC.x);
  float g1 = (a0.y + aA.y) + (aB.y + aC.y);
  float g2 = (a0.z + aA.z) + (aB.z + aC.z);
  float g3 = (a0.w + aA.w) + (aB.w + aC.w);
  float dv = dinv[d];
  float4 bb = ((const float4*)b1)[f];
  float4 a1v;
  a1v.x = fmaxf(g0 * dv + bb.x, 0.f);
  a1v.y = fmaxf(g1 * dv + bb.y, 0.f);
  a1v.z = fmaxf(g2 * dv + bb.z, 0.f);
  a1v.w = fmaxf(g3 * dv + bb.w, 0.f);
  ((float4*)arow)[slot * 17 + f] = a1v;  // stride 68 floats = 17 float4; same-wave RAW
  // fused GEMM2: lane computes output cols 2f, 2f+1 for its node
  const float* ar = &arow[slot * 68];
  float s0 = 0.f, s1 = 0.f;
#pragma unroll
  for (int kk = 0; kk < 64; ++kk) {
    float a = ar[kk];                               // 16-lane broadcast; 4 slots: 4 banks
    float2 wv = ((const float2*)w2s)[kk * 16 + f];  // 32 dwords over group: conflict-free
    s0 += a * wv.x; s1 += a * wv.y;
  }
  ((__half2*)h2s)[(size_t)d * 16 + f] = __floats2half2_rn(s0 * dv, s1 * dv);
}

// ---- gather layer 2: 8 lanes/node (lane = float2 = 4 halves), 32 nodes/block ----
// -> 8 edges per vmem instr. float4 coalesced output.
__global__ __launch_bounds__(256) void gather32_kernel(
    const __half* __restrict__ h2s, const unsigned short* __restrict__ csr,
    const int* __restrict__ eoff, const int* __restrict__ ecnt,
    const float* __restrict__ dinv, const float* __restrict__ b2,
    float* __restrict__ out, int N) {
  int t = threadIdx.x;
  int d = blockIdx.x * 32 + (t >> 3);
  if (d >= N) return;
  int f = t & 7;  // float2 column: halves 4f..4f+3
  const float2* h2p = (const float2*)h2s;  // row stride 8 float2
  int beg = eoff[d], m = ecnt[d];
  float4 a0 = unpack4(h2p[(size_t)d * 8 + f]);  // self-loop
  float4 aA = make_float4(0.f, 0.f, 0.f, 0.f);
  float4 aB = make_float4(0.f, 0.f, 0.f, 0.f);
  float4 aC = make_float4(0.f, 0.f, 0.f, 0.f);
  int j = 0;
  for (; j + 16 <= m; j += 16) {
    int s_[16];
#pragma unroll
    for (int i = 0; i < 16; ++i) s_[i] = csr[beg + j + i];
    float2 v_[16];
#pragma unroll
    for (int i = 0; i < 16; ++i) v_[i] = h2p[(size_t)s_[i] * 8 + f];
#pragma unroll
    for (int i = 0; i < 16; ++i) {
      float4 v = unpack4(v_[i]);
      float4* ac = (i & 3) == 0 ? &a0 : (i & 3) == 1 ? &aA : (i & 3) == 2 ? &aB : &aC;
      acc4(*ac, v);
    }
  }
  if (j < m) {  // masked 16-batch tail
    int s_[16];
#pragma unroll
    for (int i = 0; i < 16; ++i) { int jj = j + i; s_[i] = csr[beg + (jj < m ? jj : m - 1)]; }
    float2 v_[16];
#pragma unroll
    for (int i = 0; i < 16; ++i) v_[i] = h2p[(size_t)s_[i] * 8 + f];
#pragma unroll
    for (int i = 0; i < 16; ++i) {
      float4 v = unpack4(v_[i]);
      bool ok = (j + i < m);
      float4 vm = make_float4(ok ? v.x : 0.f, ok ? v.y : 0.f, ok ? v.z : 0.f, ok ? v.w : 0.f);
      float4* ac = (i & 3) == 0 ? &a0 : (i & 3) == 1 ? &aA : (i & 3) == 2 ? &aB : &aC;
      acc4(*ac, vm);
    }
  }
  float g0 = (a0.x + aA.x) + (aB.x + aC.x);
  float g1 = (a0.y + aA.y) + (aB.y + aC.y);
  float g2 = (a0.z + aA.z) + (aB.z + aC.z);
  float g3 = (a0.w + aA.w) + (aB.w + aC.w);
  float dv = dinv[d];
  float4 bb = ((const float4*)b2)[f];
  float4 o = make_float4(g0 * dv + bb.x, g1 * dv + bb.y, g2 * dv + bb.z, g3 * dv + bb.w);
  ((float4*)out)[(size_t)d * 8 + f] = o;
}

extern "C" void kernel_launch(void* const* d_in, const int* in_sizes, int n_in,
                              void* d_out, int out_size, void* d_ws, size_t ws_size,
                              hipStream_t stream) {
  const float* x = (const float*)d_in[0];
  const int* edge_index = (const int*)d_in[1];
  // d_in[2] = edge_attr (unused by reference)
  const float* W1 = (const float*)d_in[3];
  const float* b1 = (const float*)d_in[4];
  const float* W2 = (const float*)d_in[5];
  const float* b2 = (const float*)d_in[6];
  float* out = (float*)d_out;

  const int N = in_sizes[0] / 128;  // 50000 (key packing requires <= 65536)
  const int E = in_sizes[1] / 2;    // 800000
  const int* src = edge_index;
  const int* dst = edge_index + E;

  const int B = (N + NPB - 1) >> SHIFT;     // 196 buckets
  const int nWG = (E + CHUNK - 1) / CHUNK;  // 196 blocks

  char* ws = (char*)d_ws;
  size_t off = 0;
  auto alloc = [&](size_t bytes) -> void* {
    void* p = ws + off;
    off += (bytes + 255) & ~(size_t)255;
    return p;
  };
  unsigned* keys = (unsigned*)alloc((size_t)B * CAP * 4);        // padded bucket regions
  unsigned short* csr = (unsigned short*)alloc((size_t)B * CAP * 2);
  int* gcur = (int*)alloc((size_t)B * 4);
  int* eoff = (int*)alloc((size_t)N * 4);
  int* ecnt = (int*)alloc((size_t)N * 4);
  float* dinv = (float*)alloc((size_t)N * 4);
  __half* h1s = (__half*)alloc((size_t)N * 64 * 2);
  __half* h2s = (__half*)alloc((size_t)N * 32 * 2);

  hipMemsetAsync(gcur, 0, (size_t)B * 4, stream);
  scatter_local_kernel<<<nWG, 256, 0, stream>>>(src, dst, E, B, gcur, keys);
  bucket_build_kernel<<<B, 256, 0, stream>>>(keys, gcur, N, csr, eoff, ecnt, dinv);
  gemm1_kernel<<<(N + 63) / 64, 256, 0, stream>>>(x, W1, dinv, h1s, N);
  gather64_gemm2_kernel<<<(N + 15) / 16, 256, 0, stream>>>(h1s, csr, eoff, ecnt, dinv, b1, W2, h2s, N);
  gather32_kernel<<<(N + 31) / 32, 256, 0, stream>>>(h2s, csr, eoff, ecnt, dinv, b2, out, N);
}